// Round 7
// baseline (100.685 us; speedup 1.0000x reference)
//
#include <hip/hip_runtime.h>
#include <math.h>

// Problem constants: h [B,T,D] fp32, k scalar fp32.
#define BB 8
#define TT 2048
#define DD 512
#define LL 16             // chunk length (t-steps)
#define CC (TT / LL)      // 128 chunks per b
#define D2 (DD / 2)       // 256 float2 lanes per t-step
#define SCT 64            // superchunk length (t-steps)
#define NSC (TT / SCT)    // 32 superchunks per b
#define CPS (SCT / LL)    // 4 chunks per superchunk
#define BT (CPS * D2)     // 1024 threads per block

typedef float floatx2 __attribute__((ext_vector_type(2)));

__device__ __forceinline__ float get_s(const float* kp) {
    float k = *kp;
    return (k > 20.0f) ? k : log1pf(expf(k));   // softplus, stable
}

// ---------------------------------------------------------------------------
// R7: same dataflow as R6, thread granularity float4 -> float2.
// Blocks 512 -> 1024 threads; waves/CU 8 -> 16 (25% -> 50% occupancy).
// Mechanism under test: every stall (HBM ramp, lookback L2/L3 latency,
// barriers, 16-deep serial recurrence) now has 2x the waves to hide behind.
// Coalescing intact (64 lanes x 8 B = 512 B/instr); VALU was 4% busy so the
// 2x instruction count is free. 1024-thr blocks intrinsically cap VGPR at
// 128 (4 waves/SIMD min) -- est. usage ~70-90, no spill (R4 lesson checked).
// ---------------------------------------------------------------------------

// Kernel A: block = (b, superchunk), 1024 threads. Group jj (256 thr) owns
// chunk jj; LDS fold -> ssum/send only. Grid = 256 x 1024.
__global__ __launch_bounds__(BT, 4) void kA_stats(
    const float* __restrict__ h, const float* __restrict__ kp,
    float* __restrict__ ssum, float* __restrict__ send)
{
    const int blk = blockIdx.x;
    const int b = blk / NSC, sc = blk % NSC;
    const int tid = threadIdx.x;
    const int jj  = tid >> 8;          // chunk within superchunk, 0..3
    const int col = tid & (D2 - 1);    // float2 column, 0..255
    const float s   = get_s(kp);
    const float a   = expf(-s);
    const float a16 = expf(-s * (float)LL);

    const float2* hp = reinterpret_cast<const float2*>(h)
                     + (size_t)(b * TT + sc * SCT + jj * LL) * D2 + col;

    float sx = 0.f, sy = 0.f;          // chunk sum
    float ex = 0.f, ey = 0.f;          // chunk decayed end
    #pragma unroll
    for (int i = 0; i < LL; i++) {
        float2 x = hp[(size_t)i * D2];
        sx += x.x; sy += x.y;
        ex = fmaf(a, ex, x.x);
        ey = fmaf(a, ey, x.y);
    }

    // ---- superchunk fold via LDS (same j-order as old serial fold) -------
    __shared__ float2 lsum[CPS][D2];   // 8 KB
    __shared__ float2 lend[CPS][D2];   // 8 KB
    lsum[jj][col] = make_float2(sx, sy);
    lend[jj][col] = make_float2(ex, ey);
    __syncthreads();

    if (jj == 0) {
        float Sx = 0.f, Sy = 0.f;
        float Ex = 0.f, Ey = 0.f;
        #pragma unroll
        for (int q = 0; q < CPS; q++) {
            float2 sv = lsum[q][col];
            float2 ev = lend[q][col];
            Sx += sv.x; Sy += sv.y;
            Ex = fmaf(a16, Ex, ev.x);
            Ey = fmaf(a16, Ey, ev.y);
        }
        const size_t si = (size_t)(b * NSC + sc) * D2 + col;
        reinterpret_cast<float2*>(ssum)[si] = make_float2(Sx, Sy);
        reinterpret_cast<float2*>(send)[si] = make_float2(Ex, Ey);
    }
}

// Kernel B: block = (b, superchunk), 1024 threads. Group jj (256 thr = 4
// waves) owns chunk jj: h in registers (hv[16] float2 = 32 VGPR), chunk
// stats shared via LDS (chunk lookback reads LDS), superchunk lookback =
// proven clamped fixed-trip batch. Norm butterfly per wave + 4-partial LDS
// fold per chunk. Grid = 256 x 1024.
__global__ __launch_bounds__(BT, 4) void kB_out(
    const float* __restrict__ h, const float* __restrict__ kp,
    const float* __restrict__ ssum, const float* __restrict__ send,
    float* __restrict__ out)
{
    const int blk = blockIdx.x;
    const int b = blk / NSC, sc = blk % NSC;
    const int tid = threadIdx.x;
    const int jj  = tid >> 8;          // chunk within superchunk, 0..3
    const int col = tid & (D2 - 1);    // float2 column, 0..255
    const int gw   = (tid >> 6) & 3;   // wave within group, 0..3
    const int lane = tid & 63;
    const float s   = get_s(kp);
    const float a   = expf(-s);
    const float a16 = expf(-s * (float)LL);
    const float aSC = expf(-s * (float)SCT);

    const int t0 = sc * SCT + jj * LL;
    const float2* hp = reinterpret_cast<const float2*>(h)
                     + (size_t)(b * TT + t0) * D2 + col;

    __shared__ float2 lsum[CPS][D2];   // 8 KB: chunk sums
    __shared__ float2 lend[CPS][D2];   // 8 KB: chunk decayed ends
    __shared__ float part[CPS][4][LL]; // 1 KB

    // ---- h chunk -> registers + chunk stats (same order as kA) -----------
    float2 hv[LL];                                   // 32 VGPRs
    float sx = 0.f, sy = 0.f;
    float ex = 0.f, ey = 0.f;
    #pragma unroll
    for (int i = 0; i < LL; i++) {
        float2 x = hp[(size_t)i * D2];
        hv[i] = x;
        sx += x.x; sy += x.y;
        ex = fmaf(a, ex, x.x);
        ey = fmaf(a, ey, x.y);
    }
    lsum[jj][col] = make_float2(sx, sy);
    lend[jj][col] = make_float2(ex, ey);

    float px = 0.f, py = 0.f;                        // h[t0-1]
    if (t0 > 0) {
        float2 pv = *(hp - (ptrdiff_t)D2);
        px = pv.x; py = pv.y;
    }

    // ---- lookback level 1: superchunks before sc (batched, clamped) ------
    float cox = 0.f, coy = 0.f;        // cumsum offset
    float ccx = 0.f, ccy = 0.f;        // ctx entering state
    if (sc > 0) {
        const float2* ss2 = reinterpret_cast<const float2*>(ssum)
                          + (size_t)(b * NSC) * D2 + col;
        const float2* se2 = reinterpret_cast<const float2*>(send)
                          + (size_t)(b * NSC) * D2 + col;
        float w = 1.f;                      // aSC^d (descending weights)
        #pragma unroll
        for (int d = 0; d < NSC - 1; d++) {
            const int   q    = (d < sc) ? (sc - 1 - d) : 0;   // clamped addr
            const float live = (d < sc) ? 1.f : 0.f;
            float2 sv = ss2[(size_t)q * D2];
            float2 ev = se2[(size_t)q * D2];
            cox = fmaf(live, sv.x, cox);
            coy = fmaf(live, sv.y, coy);
            const float wl = w * live;
            ccx = fmaf(wl, ev.x, ccx);
            ccy = fmaf(wl, ev.y, ccy);
            w *= aSC;
        }
    }

    __syncthreads();   // chunk stats of all 4 groups visible in LDS

    // ---- lookback level 2: chunks before jj, from LDS --------------------
    if (jj > 0) {
        float cIx = 0.f, cIy = 0.f;
        float w = 1.f;                      // a16^d (descending weights)
        #pragma unroll
        for (int d = 0; d < CPS - 1; d++) {
            const int   q    = (d < jj) ? (jj - 1 - d) : 0;   // clamped addr
            const float live = (d < jj) ? 1.f : 0.f;
            float2 sv = lsum[q][col];
            float2 ev = lend[q][col];
            cox = fmaf(live, sv.x, cox);
            coy = fmaf(live, sv.y, coy);
            const float wl = w * live;
            cIx = fmaf(wl, ev.x, cIx);
            cIy = fmaf(wl, ev.y, cIy);
            w *= a16;
        }
        // ctx entering chunk = (superchunk carry) * a16^jj + intra part
        const float a32 = a16 * a16;
        const float wj  = (jj == 1) ? a16 : (jj == 2) ? a32 : a32 * a16;
        ccx = fmaf(wj, ccx, cIx);
        ccy = fmaf(wj, ccy, cIy);
    }

    // ---- pass A: cumsum chain from registers -----------------------------
    float r[LL];
    #pragma unroll
    for (int i = 0; i < LL; i++) {
        float2 x = hv[i];
        cox += x.x; coy += x.y;
        float dx = cox - px, dy = coy - py;
        r[i] = dx * dx + dy * dy;
        px = x.x; py = x.y;
    }

    // batched butterfly: 6 rounds x 16 independent values (within wave)
    #pragma unroll
    for (int m = 1; m < 64; m <<= 1) {
        #pragma unroll
        for (int i = 0; i < LL; i++) r[i] += __shfl_xor(r[i], m, 64);
    }
    if (lane == 0) {
        #pragma unroll
        for (int i = 0; i < LL; i++) part[jj][gw][i] = r[i];
    }
    __syncthreads();

    float mag[LL];
    #pragma unroll
    for (int i = 0; i < LL; i++)
        mag[i] = sqrtf((part[jj][0][i] + part[jj][1][i])
                     + (part[jj][2][i] + part[jj][3][i]));

    // ---- pass B: ctx recurrence from registers, non-temporal store -------
    floatx2* op = reinterpret_cast<floatx2*>(out)
                + (size_t)(b * TT + t0) * D2 + col;
    #pragma unroll
    for (int i = 0; i < LL; i++) {
        float2 x = hv[i];
        ccx = fmaf(a, ccx, x.x);
        ccy = fmaf(a, ccy, x.y);
        float m = mag[i];
        floatx2 o;
        o.x = fabsf(m * ccx);
        o.y = fabsf(m * ccy);
        __builtin_nontemporal_store(o, op + (size_t)i * D2);
    }
}

extern "C" void kernel_launch(void* const* d_in, const int* in_sizes, int n_in,
                              void* d_out, int out_size, void* d_ws, size_t ws_size,
                              hipStream_t stream) {
    const float* h  = (const float*)d_in[0];
    const float* kp = (const float*)d_in[1];
    float* out = (float*)d_out;

    const size_t NSb = (size_t)BB * NSC * DD;   // 128K floats = 512 KB each
    float* ssum = (float*)d_ws;
    float* send = ssum + NSb;

    kA_stats<<<dim3(BB * NSC), dim3(BT), 0, stream>>>(h, kp, ssum, send);
    kB_out  <<<dim3(BB * NSC), dim3(BT), 0, stream>>>(h, kp, ssum, send, out);
}